// Round 1
// baseline (677.287 us; speedup 1.0000x reference)
//
#include <hip/hip_runtime.h>
#include <hip/hip_bf16.h>

#define BB 2
#define SS 513
#define HH 512
#define NHH 8
#define DDIM 64

// ---------------------------------------------------------------------------
// Detect graph buffer layout: bool (1 byte/elem) vs int32/float32 (4 byte/elem).
// For 4-byte layouts holding 0/1 (or 0.0/1.0), every byte at offset %4==1 is 0.
// For bool layout, ~50% of those bytes are 1. Writes flag=1 for bool layout.
__global__ __launch_bounds__(256) void detect_kernel(const unsigned char* __restrict__ g,
                                                     int* __restrict__ flag) {
  __shared__ int s;
  if (threadIdx.x == 0) s = 0;
  __syncthreads();
  const long n = (long)BB * SS * SS;
  int local = 0;
  for (long i = (long)threadIdx.x * 4 + 1; i < n; i += 1024)
    local |= g[i];
  if (local) atomicOr(&s, 1);
  __syncthreads();
  if (threadIdx.x == 0) *flag = s;
}

__device__ __forceinline__ bool graph_at(const void* g, int isBool, size_t idx) {
  if (isBool) return ((const unsigned char*)g)[idx] != 0;
  return ((const int*)g)[idx] != 0;  // also correct for float32 0.0/1.0 bit patterns
}

// ---------------------------------------------------------------------------
// Prep: y[b,t,o] = sum_h W[f(t)][o][h] * x[b,t,h] + sum_f bias[f][o]
// Rows grouped by class f so each block streams one W slice for 16 rows.
// grid.x = 3 tensors * 2 b * 34 chunks = 204
__global__ __launch_bounds__(256) void prep_kernel(
    const float* __restrict__ Xq, const float* __restrict__ Xk, const float* __restrict__ Xv,
    const float* __restrict__ Wq, const float* __restrict__ Wk, const float* __restrict__ Wv,
    const float* __restrict__ Bq, const float* __restrict__ Bk, const float* __restrict__ Bv,
    float* __restrict__ Yq, float* __restrict__ Yk, float* __restrict__ Yv) {
  __shared__ float xs[16][HH];
  int idx = blockIdx.x;
  int tb = idx / 34, rem = idx % 34;
  int tensor = tb >> 1, b = tb & 1;
  int f, chunk;
  if (rem < 4)       { f = 0; chunk = rem; }
  else if (rem < 8)  { f = 1; chunk = rem - 4; }
  else if (rem < 12) { f = 2; chunk = rem - 8; }
  else if (rem < 23) { f = 3; chunk = rem - 12; }
  else               { f = 4; chunk = rem - 23; }
  const int count = (f < 3) ? 57 : 171;
  const float* X  = (tensor == 0) ? Xq : (tensor == 1) ? Xk : Xv;
  const float* W  = (tensor == 0) ? Wq : (tensor == 1) ? Wk : Wv;
  const float* Bi = (tensor == 0) ? Bq : (tensor == 1) ? Bk : Bv;
  float* Y        = (tensor == 0) ? Yq : (tensor == 1) ? Yk : Yv;
  const int tid = threadIdx.x;

  for (int r = 0; r < 16; ++r) {
    int i = chunk * 16 + r;
    if (i < count) {
      int t = (f < 3) ? (f + 9 * i) : (f + 2 * (i % 3) + 9 * (i / 3));
      const float* src = X + (size_t)(b * SS + t) * HH;
      xs[r][tid] = src[tid];
      xs[r][tid + 256] = src[tid + 256];
    }
  }
  __syncthreads();

  const int o0 = tid, o1 = tid + 256;
  const float* w0 = W + (size_t)f * HH * HH + (size_t)o0 * HH;
  const float* w1 = w0 + 256 * HH;
  float acc0[16], acc1[16];
#pragma unroll
  for (int r = 0; r < 16; ++r) { acc0[r] = 0.f; acc1[r] = 0.f; }
  for (int hc = 0; hc < HH / 4; ++hc) {
    float4 a = *(const float4*)(w0 + hc * 4);
    float4 c = *(const float4*)(w1 + hc * 4);
#pragma unroll
    for (int r = 0; r < 16; ++r) {
      float4 x4 = *(const float4*)&xs[r][hc * 4];
      acc0[r] += a.x * x4.x + a.y * x4.y + a.z * x4.z + a.w * x4.w;
      acc1[r] += c.x * x4.x + c.y * x4.y + c.z * x4.z + c.w * x4.w;
    }
  }
  float bs0 = 0.f, bs1 = 0.f;
#pragma unroll
  for (int ff = 0; ff < 5; ++ff) { bs0 += Bi[ff * HH + o0]; bs1 += Bi[ff * HH + o1]; }

  for (int r = 0; r < 16; ++r) {
    int i = chunk * 16 + r;
    if (i < count) {
      int t = (f < 3) ? (f + 9 * i) : (f + 2 * (i % 3) + 9 * (i / 3));
      float* dst = Y + (size_t)(b * SS + t) * HH;
      dst[o0] = acc0[r] + bs0;
      dst[o1] = acc1[r] + bs1;
    }
  }
}

// ---------------------------------------------------------------------------
// Partial V-sum over keys: part[p][b*HH+o] = sum_{t=p, step 8} V[b,t,o]
// grid.x = 32  (p = bid>>2, output chunk = bid&3)
__global__ __launch_bounds__(256) void vsum_part_kernel(const float* __restrict__ V,
                                                        float* __restrict__ part) {
  int idx = (blockIdx.x & 3) * 256 + threadIdx.x;  // 0..1023 -> (b,o)
  int p = blockIdx.x >> 2;                         // 0..7
  int b = idx >> 9, o = idx & 511;
  float acc = 0.f;
  for (int t = p; t < SS; t += 8)
    acc += V[(size_t)(b * SS + t) * HH + o];
  part[p * 1024 + idx] = acc;
}

// ---------------------------------------------------------------------------
// Sparse attention. One block per (b,q).
// score[h,k] = sum_d (Q[h*64+d] + eq[b,k,q,d]) * (K[b,k,h*64+d] + ek[b,q,k,d])
// q>=3: candidates {0,1,2,g,g+1}; q<3: all 513. Masked -> weight 0 exactly.
// All-masked row -> uniform 1/513 over ALL keys (matches jax softmax of -1e5 row).
__global__ __launch_bounds__(256) void attn_kernel(
    const float* __restrict__ Q, const float* __restrict__ K, const float* __restrict__ V,
    const float* __restrict__ vsumPart, const void* __restrict__ graph,
    const int* __restrict__ flag,
    const float* __restrict__ EK, const float* __restrict__ EV, const float* __restrict__ EQ,
    float* __restrict__ X) {
  __shared__ float sQ[HH];
  __shared__ float sS[SS * NHH];
  __shared__ float sRed[4 * 64];
  __shared__ int sUni;

  const int tid = threadIdx.x, lane = tid & 63, wv = tid >> 6;
  const int bq = blockIdx.x;
  const int b = bq / SS, q = bq % SS;
  const int isBool = *flag;

  sQ[tid] = Q[(size_t)bq * HH + tid];
  sQ[tid + 256] = Q[(size_t)bq * HH + tid + 256];
  if (tid == 0) sUni = 0;
  __syncthreads();

  const int ncand = (q < 3) ? SS : 5;
  const int g = (q >= 3) ? (3 + ((q - 3) >> 1) * 2) : 0;
  const size_t gbase = (size_t)b * SS * SS + (size_t)q * SS;

  // ---- scores ----
  for (int c = wv; c < ncand; c += 4) {
    int k = (q < 3) ? c : (c < 3 ? c : g + (c - 3));
    bool m = graph_at(graph, isBool, gbase + k);
    if (!m) {
      if (lane < NHH) sS[c * NHH + lane] = -1e30f;
    } else {
      float ekd = EK[((size_t)(b * SS + q) * SS + k) * DDIM + lane];
      float eqd = EQ[((size_t)(b * SS + k) * SS + q) * DDIM + lane];
      const float* Kr = K + (size_t)(b * SS + k) * HH;
#pragma unroll
      for (int h = 0; h < NHH; ++h) {
        float p = (sQ[h * 64 + lane] + eqd) * (Kr[h * 64 + lane] + ekd);
#pragma unroll
        for (int off = 32; off; off >>= 1) p += __shfl_xor(p, off);
        if (lane == 0) sS[c * NHH + h] = p * 0.125f;
      }
    }
  }
  __syncthreads();

  // ---- softmax per head (wave wv handles heads wv, wv+4) ----
  for (int h = wv; h < NHH; h += 4) {
    float mx = -3e38f;
    for (int c = lane; c < ncand; c += 64) mx = fmaxf(mx, sS[c * NHH + h]);
#pragma unroll
    for (int off = 32; off; off >>= 1) mx = fmaxf(mx, __shfl_xor(mx, off));
    if (mx < -1e29f) {
      if (h == 0 && lane == 0) sUni = 1;  // mask is head-independent
    } else {
      float sum = 0.f;
      for (int c = lane; c < ncand; c += 64) {
        float e = __expf(sS[c * NHH + h] - mx);  // -1e30 sentinel underflows to 0
        sS[c * NHH + h] = e;
        sum += e;
      }
#pragma unroll
      for (int off = 32; off; off >>= 1) sum += __shfl_xor(sum, off);
      float inv = 1.f / sum;
      for (int c = lane; c < ncand; c += 64) sS[c * NHH + h] *= inv;
    }
  }
  __syncthreads();

  // ---- output ----
  if (sUni) {
    // uniform 1/513 over ALL keys: x = (sum_k V + sum_k EV_row) / 513
    float acc = 0.f;
    for (int k = wv; k < SS; k += 4)
      acc += EV[((size_t)(b * SS + q) * SS + k) * DDIM + lane];
    sRed[wv * 64 + lane] = acc;
    __syncthreads();
    if (tid < 64) sRed[tid] = sRed[tid] + sRed[64 + tid] + sRed[128 + tid] + sRed[192 + tid];
    __syncthreads();
    const float c0 = 1.0f / 513.0f;
    for (int o = tid; o < HH; o += 256) {
      float vs = 0.f;
#pragma unroll
      for (int p = 0; p < 8; ++p) vs += vsumPart[p * 1024 + b * HH + o];
      X[(size_t)bq * HH + o] = (vs + sRed[o & 63]) * c0;
    }
  } else {
#pragma unroll
    for (int rep = 0; rep < 2; ++rep) {
      int o = tid + rep * 256;
      int hh = o >> 6, d = o & 63;
      float acc = 0.f;
      for (int c = 0; c < ncand; ++c) {
        float w = sS[c * NHH + hh];  // wave-uniform (hh uniform per wave)
        if (w != 0.f) {
          int k = (q < 3) ? c : (c < 3 ? c : g + (c - 3));
          acc += w * (V[(size_t)(b * SS + k) * HH + o] +
                      EV[((size_t)(b * SS + q) * SS + k) * DDIM + d]);
        }
      }
      X[(size_t)bq * HH + o] = acc;
    }
  }
}

// ---------------------------------------------------------------------------
// out[row,o] = sum_h X[row,h] * Wo[o,h] + bo[o].  grid = (65, 2)
__global__ __launch_bounds__(256) void proj_kernel(const float* __restrict__ Xin,
                                                   const float* __restrict__ Wo,
                                                   const float* __restrict__ bo,
                                                   float* __restrict__ out) {
  __shared__ float xs[16][HH];
  const int chunk = blockIdx.x;
  const int tid = threadIdx.x;
  const int NROW = BB * SS;
  for (int r = 0; r < 16; ++r) {
    int row = chunk * 16 + r;
    if (row < NROW) {
      const float* src = Xin + (size_t)row * HH;
      xs[r][tid] = src[tid];
      xs[r][tid + 256] = src[tid + 256];
    }
  }
  __syncthreads();
  const int o = blockIdx.y * 256 + tid;
  const float* w = Wo + (size_t)o * HH;
  float acc[16];
#pragma unroll
  for (int r = 0; r < 16; ++r) acc[r] = 0.f;
  for (int hc = 0; hc < HH / 4; ++hc) {
    float4 wv4 = *(const float4*)(w + hc * 4);
#pragma unroll
    for (int r = 0; r < 16; ++r) {
      float4 x4 = *(const float4*)&xs[r][hc * 4];
      acc[r] += wv4.x * x4.x + wv4.y * x4.y + wv4.z * x4.z + wv4.w * x4.w;
    }
  }
  const float bias = bo[o];
  for (int r = 0; r < 16; ++r) {
    int row = chunk * 16 + r;
    if (row < NROW) out[(size_t)row * HH + o] = acc[r] + bias;
  }
}

// ---------------------------------------------------------------------------
extern "C" void kernel_launch(void* const* d_in, const int* in_sizes, int n_in,
                              void* d_out, int out_size, void* d_ws, size_t ws_size,
                              hipStream_t stream) {
  (void)in_sizes; (void)n_in; (void)out_size; (void)ws_size;
  const float* query = (const float*)d_in[0];
  const float* key   = (const float*)d_in[1];
  const float* value = (const float*)d_in[2];
  const void*  graph = d_in[3];
  const float* EK = (const float*)d_in[4];
  const float* EV = (const float*)d_in[5];
  const float* EQ = (const float*)d_in[6];
  const float* Wq = (const float*)d_in[7];
  const float* bq = (const float*)d_in[8];
  const float* Wk = (const float*)d_in[9];
  const float* bk = (const float*)d_in[10];
  const float* Wv = (const float*)d_in[11];
  const float* bv = (const float*)d_in[12];
  const float* Wo = (const float*)d_in[13];
  const float* bo = (const float*)d_in[14];
  float* out = (float*)d_out;

  char* ws = (char*)d_ws;
  int*   flag = (int*)ws;                       // 4 B
  float* part = (float*)(ws + 256);             // 8*1024*4 = 32 KB
  float* Qp = (float*)(ws + 40960);             // 2101248 B each
  float* Kp = (float*)(ws + 40960 + 2101248);
  float* Vp = (float*)(ws + 40960 + 2 * 2101248);
  float* Xp = (float*)(ws + 40960 + 3 * 2101248);

  detect_kernel<<<1, 256, 0, stream>>>((const unsigned char*)graph, flag);
  prep_kernel<<<204, 256, 0, stream>>>(query, key, value, Wq, Wk, Wv, bq, bk, bv,
                                       Qp, Kp, Vp);
  vsum_part_kernel<<<32, 256, 0, stream>>>(Vp, part);
  attn_kernel<<<BB * SS, 256, 0, stream>>>(Qp, Kp, Vp, part, graph, flag,
                                           EK, EV, EQ, Xp);
  proj_kernel<<<dim3(65, 2), 256, 0, stream>>>(Xp, Wo, bo, out);
}

// Round 2
// 332.920 us; speedup vs baseline: 2.0344x; 2.0344x over previous
//
#include <hip/hip_runtime.h>
#include <hip/hip_bf16.h>

#define BB 2
#define SS 513
#define HH 512
#define NHH 8
#define DDIM 64

// ---------------------------------------------------------------------------
// Detect graph buffer layout: bool (1 byte/elem) vs int32/float32 (4 byte/elem).
// For 4-byte layouts holding 0/1 (or 0.0f/1.0f), byte at offset %4==1 is always 0.
// For bool layout, ~50% of those bytes are 1. Scan first 128 KB vectorized.
__global__ __launch_bounds__(256) void detect_kernel(const uint4* __restrict__ gv,
                                                     int* __restrict__ flag) {
  __shared__ int s;
  if (threadIdx.x == 0) s = 0;
  __syncthreads();
  unsigned int local = 0;
  for (int i = threadIdx.x; i < 8192; i += 256) {  // 8192*16B = 128 KB
    uint4 v = gv[i];
    local |= (v.x | v.y | v.z | v.w) & 0x0000ff00u;
  }
  if (local) atomicOr(&s, 1);
  __syncthreads();
  if (threadIdx.x == 0) *flag = s;
}

__device__ __forceinline__ bool graph_at(const void* g, int isBool, size_t idx) {
  if (isBool) return ((const unsigned char*)g)[idx] != 0;
  return ((const int*)g)[idx] != 0;  // also correct for float32 0.0/1.0 bit patterns
}

// ---------------------------------------------------------------------------
// Prep: y[b,t,o] = sum_h W[f(t)][o][h] * x[b,t,h] + sum_f bias[f][o]
// Rows grouped by class f so each block streams one W slice for 16 rows.
// grid.x = 3 tensors * 2 b * 34 chunks = 204
__global__ __launch_bounds__(256) void prep_kernel(
    const float* __restrict__ Xq, const float* __restrict__ Xk, const float* __restrict__ Xv,
    const float* __restrict__ Wq, const float* __restrict__ Wk, const float* __restrict__ Wv,
    const float* __restrict__ Bq, const float* __restrict__ Bk, const float* __restrict__ Bv,
    float* __restrict__ Yq, float* __restrict__ Yk, float* __restrict__ Yv) {
  __shared__ float xs[16][HH];
  int idx = blockIdx.x;
  int tb = idx / 34, rem = idx % 34;
  int tensor = tb >> 1, b = tb & 1;
  int f, chunk;
  if (rem < 4)       { f = 0; chunk = rem; }
  else if (rem < 8)  { f = 1; chunk = rem - 4; }
  else if (rem < 12) { f = 2; chunk = rem - 8; }
  else if (rem < 23) { f = 3; chunk = rem - 12; }
  else               { f = 4; chunk = rem - 23; }
  const int count = (f < 3) ? 57 : 171;
  const float* X  = (tensor == 0) ? Xq : (tensor == 1) ? Xk : Xv;
  const float* W  = (tensor == 0) ? Wq : (tensor == 1) ? Wk : Wv;
  const float* Bi = (tensor == 0) ? Bq : (tensor == 1) ? Bk : Bv;
  float* Y        = (tensor == 0) ? Yq : (tensor == 1) ? Yk : Yv;
  const int tid = threadIdx.x;

  for (int r = 0; r < 16; ++r) {
    int i = chunk * 16 + r;
    if (i < count) {
      int t = (f < 3) ? (f + 9 * i) : (f + 2 * (i % 3) + 9 * (i / 3));
      const float* src = X + (size_t)(b * SS + t) * HH;
      xs[r][tid] = src[tid];
      xs[r][tid + 256] = src[tid + 256];
    }
  }
  __syncthreads();

  const int o0 = tid, o1 = tid + 256;
  const float* w0 = W + (size_t)f * HH * HH + (size_t)o0 * HH;
  const float* w1 = w0 + 256 * HH;
  float acc0[16], acc1[16];
#pragma unroll
  for (int r = 0; r < 16; ++r) { acc0[r] = 0.f; acc1[r] = 0.f; }
  for (int hc = 0; hc < HH / 4; ++hc) {
    float4 a = *(const float4*)(w0 + hc * 4);
    float4 c = *(const float4*)(w1 + hc * 4);
#pragma unroll
    for (int r = 0; r < 16; ++r) {
      float4 x4 = *(const float4*)&xs[r][hc * 4];
      acc0[r] += a.x * x4.x + a.y * x4.y + a.z * x4.z + a.w * x4.w;
      acc1[r] += c.x * x4.x + c.y * x4.y + c.z * x4.z + c.w * x4.w;
    }
  }
  float bs0 = 0.f, bs1 = 0.f;
#pragma unroll
  for (int ff = 0; ff < 5; ++ff) { bs0 += Bi[ff * HH + o0]; bs1 += Bi[ff * HH + o1]; }

  for (int r = 0; r < 16; ++r) {
    int i = chunk * 16 + r;
    if (i < count) {
      int t = (f < 3) ? (f + 9 * i) : (f + 2 * (i % 3) + 9 * (i / 3));
      float* dst = Y + (size_t)(b * SS + t) * HH;
      dst[o0] = acc0[r] + bs0;
      dst[o1] = acc1[r] + bs1;
    }
  }
}

// ---------------------------------------------------------------------------
// Partial V-sum over keys: part[p][b*HH+o] = sum_{t=p, step 8} V[b,t,o]
__global__ __launch_bounds__(256) void vsum_part_kernel(const float* __restrict__ V,
                                                        float* __restrict__ part) {
  int idx = (blockIdx.x & 3) * 256 + threadIdx.x;  // 0..1023 -> (b,o)
  int p = blockIdx.x >> 2;                         // 0..7
  int b = idx >> 9, o = idx & 511;
  float acc = 0.f;
  for (int t = p; t < SS; t += 8)
    acc += V[(size_t)(b * SS + t) * HH + o];
  part[p * 1024 + idx] = acc;
}

// ---------------------------------------------------------------------------
// Sparse attention, q >= 3 only. One block per (b,q). Candidates {0,1,2,g,g+1}.
// All loads unconditional so VMEM pipelines; mask applied via select / w=0.
__global__ __launch_bounds__(256) void attn_sparse_kernel(
    const float* __restrict__ Q, const float* __restrict__ K, const float* __restrict__ V,
    const float* __restrict__ vsumPart, const void* __restrict__ graph,
    const int* __restrict__ flag,
    const float* __restrict__ EK, const float* __restrict__ EV, const float* __restrict__ EQ,
    float* __restrict__ X) {
  __shared__ float sQ[HH];
  __shared__ float sW[5 * NHH];
  __shared__ float sRed[4 * 64];
  __shared__ int sUni;

  const int tid = threadIdx.x, lane = tid & 63, wv = tid >> 6;
  const int bid = blockIdx.x;
  const int b = bid / 510, q = 3 + bid % 510;
  const int row = b * SS + q;
  const int isBool = *flag;

  sQ[tid] = Q[(size_t)row * HH + tid];
  sQ[tid + 256] = Q[(size_t)row * HH + tid + 256];
  if (tid == 0) sUni = 0;
  __syncthreads();

  const int g = 3 + ((q - 3) >> 1) * 2;
  const size_t gbase = (size_t)b * SS * SS + (size_t)q * SS;

  // ---- scores: 5 candidates over 4 waves (wave 0 takes c=0,4) ----
  for (int c = wv; c < 5; c += 4) {
    int k = (c < 3) ? c : g + (c - 3);
    bool m = graph_at(graph, isBool, gbase + k);
    float ekd = EK[(gbase + k) * DDIM + lane];
    float eqd = EQ[((size_t)(b * SS + k) * SS + q) * DDIM + lane];
    const float* Kr = K + (size_t)(b * SS + k) * HH;
#pragma unroll
    for (int h = 0; h < NHH; ++h) {
      float p = (sQ[h * 64 + lane] + eqd) * (Kr[h * 64 + lane] + ekd);
#pragma unroll
      for (int off = 32; off; off >>= 1) p += __shfl_xor(p, off);
      if (lane == 0) sW[c * NHH + h] = m ? p * 0.125f : -1e30f;
    }
  }
  __syncthreads();

  // ---- softmax: wave 0, lane -> (h = lane>>3, c = lane&7; c>=5 padded) ----
  if (wv == 0) {
    int h = lane >> 3, c = lane & 7;
    float s = (c < 5) ? sW[c * NHH + h] : -1e30f;
    float mx = s;
#pragma unroll
    for (int off = 4; off; off >>= 1) mx = fmaxf(mx, __shfl_xor(mx, off));
    float e = (mx < -1e29f) ? 0.f : __expf(s - mx);  // masked: exp underflows to 0
    float sum = e;
#pragma unroll
    for (int off = 4; off; off >>= 1) sum += __shfl_xor(sum, off);
    if (c < 5) sW[c * NHH + h] = (mx < -1e29f) ? 0.f : e / sum;
    if (lane == 0 && mx < -1e29f) sUni = 1;  // mask is head-independent
  }
  __syncthreads();

  // ---- output ----
  if (sUni) {
    // uniform 1/513 over ALL keys: x = (sum_k V + sum_k EV_row) / 513
    float acc = 0.f;
    for (int k = wv; k < SS; k += 4)
      acc += EV[(gbase + k) * DDIM + lane];
    sRed[wv * 64 + lane] = acc;
    __syncthreads();
    if (tid < 64) sRed[tid] = sRed[tid] + sRed[64 + tid] + sRed[128 + tid] + sRed[192 + tid];
    __syncthreads();
    const float c0 = 1.0f / 513.0f;
    for (int o = tid; o < HH; o += 256) {
      float vs = 0.f;
#pragma unroll
      for (int p = 0; p < 8; ++p) vs += vsumPart[p * 1024 + b * HH + o];
      X[(size_t)row * HH + o] = (vs + sRed[o & 63]) * c0;
    }
  } else {
#pragma unroll
    for (int rep = 0; rep < 2; ++rep) {
      int o = tid + rep * 256;
      int hh = o >> 6, d = o & 63;
      float acc = 0.f;
#pragma unroll
      for (int c = 0; c < 5; ++c) {
        int k = (c < 3) ? c : g + (c - 3);
        acc += sW[c * NHH + hh] *
               (V[(size_t)(b * SS + k) * HH + o] + EV[(gbase + k) * DDIM + d]);
      }
      X[(size_t)row * HH + o] = acc;
    }
  }
}

// ---------------------------------------------------------------------------
// Dense attention, q < 3. One block per (b,q,h): grid = 2*3*8 = 48.
__global__ __launch_bounds__(256) void attn_dense_kernel(
    const float* __restrict__ Q, const float* __restrict__ K, const float* __restrict__ V,
    const float* __restrict__ vsumPart, const void* __restrict__ graph,
    const int* __restrict__ flag,
    const float* __restrict__ EK, const float* __restrict__ EV, const float* __restrict__ EQ,
    float* __restrict__ X) {
  __shared__ float sS[SS];
  __shared__ float sRed[8];
  __shared__ float sOut[4][DDIM];

  const int tid = threadIdx.x, lane = tid & 63, wv = tid >> 6;
  const int bid = blockIdx.x;
  const int b = bid / 24, r2 = bid % 24, q = r2 >> 3, h = r2 & 7;
  const int row = b * SS + q;
  const int isBool = *flag;
  const size_t gbase = (size_t)b * SS * SS + (size_t)q * SS;
  const float qd = Q[(size_t)row * HH + h * 64 + lane];

  // ---- scores: k parallel over waves, d = lane, shfl reduce ----
  for (int k = wv; k < SS; k += 4) {
    bool m = graph_at(graph, isBool, gbase + k);
    float ekd = EK[(gbase + k) * DDIM + lane];
    float eqd = EQ[((size_t)(b * SS + k) * SS + q) * DDIM + lane];
    float kd = K[(size_t)(b * SS + k) * HH + h * 64 + lane];
    float p = (qd + eqd) * (kd + ekd);
#pragma unroll
    for (int off = 32; off; off >>= 1) p += __shfl_xor(p, off);
    if (lane == 0) sS[k] = m ? p * 0.125f : -1e30f;
  }
  __syncthreads();

  // ---- block max over 513 ----
  float mx = -3e38f;
  for (int k = tid; k < SS; k += 256) mx = fmaxf(mx, sS[k]);
#pragma unroll
  for (int off = 32; off; off >>= 1) mx = fmaxf(mx, __shfl_xor(mx, off));
  if (lane == 0) sRed[wv] = mx;
  __syncthreads();
  mx = fmaxf(fmaxf(sRed[0], sRed[1]), fmaxf(sRed[2], sRed[3]));

  if (mx < -1e29f) {
    // all masked -> uniform 1/513 over all keys (practically unreachable, exactness)
    float acc = 0.f;
    for (int k = wv; k < SS; k += 4) acc += EV[(gbase + k) * DDIM + lane];
    sOut[wv][lane] = acc;
    __syncthreads();
    if (tid < 64) {
      float tot = sOut[0][lane] + sOut[1][lane] + sOut[2][lane] + sOut[3][lane];
      float vs = 0.f;
#pragma unroll
      for (int p = 0; p < 8; ++p) vs += vsumPart[p * 1024 + b * HH + h * 64 + lane];
      X[(size_t)row * HH + h * 64 + lane] = (vs + tot) * (1.0f / 513.0f);
    }
    return;
  }

  // ---- exp + sum ----
  float sum = 0.f;
  for (int k = tid; k < SS; k += 256) {
    float e = __expf(sS[k] - mx);  // masked sentinel underflows to exactly 0
    sS[k] = e;
    sum += e;
  }
#pragma unroll
  for (int off = 32; off; off >>= 1) sum += __shfl_xor(sum, off);
  if (lane == 0) sRed[4 + wv] = sum;
  __syncthreads();
  const float inv = 1.0f / (sRed[4] + sRed[5] + sRed[6] + sRed[7]);

  // ---- output: k parallel over waves, unconditional pipelined loads ----
  float acc = 0.f;
  for (int k = wv; k < SS; k += 4) {
    float w = sS[k];
    acc += w * (V[(size_t)(b * SS + k) * HH + h * 64 + lane] +
                EV[(gbase + k) * DDIM + lane]);
  }
  sOut[wv][lane] = acc;
  __syncthreads();
  if (tid < 64)
    X[(size_t)row * HH + h * 64 + lane] =
        (sOut[0][lane] + sOut[1][lane] + sOut[2][lane] + sOut[3][lane]) * inv;
}

// ---------------------------------------------------------------------------
// out[row,o] = sum_h X[row,h] * Wo[o,h] + bo[o].  grid = (65, 2)
__global__ __launch_bounds__(256) void proj_kernel(const float* __restrict__ Xin,
                                                   const float* __restrict__ Wo,
                                                   const float* __restrict__ bo,
                                                   float* __restrict__ out) {
  __shared__ float xs[16][HH];
  const int chunk = blockIdx.x;
  const int tid = threadIdx.x;
  const int NROW = BB * SS;
  for (int r = 0; r < 16; ++r) {
    int row = chunk * 16 + r;
    if (row < NROW) {
      const float* src = Xin + (size_t)row * HH;
      xs[r][tid] = src[tid];
      xs[r][tid + 256] = src[tid + 256];
    }
  }
  __syncthreads();
  const int o = blockIdx.y * 256 + tid;
  const float* w = Wo + (size_t)o * HH;
  float acc[16];
#pragma unroll
  for (int r = 0; r < 16; ++r) acc[r] = 0.f;
  for (int hc = 0; hc < HH / 4; ++hc) {
    float4 wv4 = *(const float4*)(w + hc * 4);
#pragma unroll
    for (int r = 0; r < 16; ++r) {
      float4 x4 = *(const float4*)&xs[r][hc * 4];
      acc[r] += wv4.x * x4.x + wv4.y * x4.y + wv4.z * x4.z + wv4.w * x4.w;
    }
  }
  const float bias = bo[o];
  for (int r = 0; r < 16; ++r) {
    int row = chunk * 16 + r;
    if (row < NROW) out[(size_t)row * HH + o] = acc[r] + bias;
  }
}

// ---------------------------------------------------------------------------
extern "C" void kernel_launch(void* const* d_in, const int* in_sizes, int n_in,
                              void* d_out, int out_size, void* d_ws, size_t ws_size,
                              hipStream_t stream) {
  (void)in_sizes; (void)n_in; (void)out_size; (void)ws_size;
  const float* query = (const float*)d_in[0];
  const float* key   = (const float*)d_in[1];
  const float* value = (const float*)d_in[2];
  const void*  graph = d_in[3];
  const float* EK = (const float*)d_in[4];
  const float* EV = (const float*)d_in[5];
  const float* EQ = (const float*)d_in[6];
  const float* Wq = (const float*)d_in[7];
  const float* bq = (const float*)d_in[8];
  const float* Wk = (const float*)d_in[9];
  const float* bk = (const float*)d_in[10];
  const float* Wv = (const float*)d_in[11];
  const float* bv = (const float*)d_in[12];
  const float* Wo = (const float*)d_in[13];
  const float* bo = (const float*)d_in[14];
  float* out = (float*)d_out;

  char* ws = (char*)d_ws;
  int*   flag = (int*)ws;                       // 4 B
  float* part = (float*)(ws + 256);             // 32 KB
  float* Qp = (float*)(ws + 40960);             // 2101248 B each
  float* Kp = (float*)(ws + 40960 + 2101248);
  float* Vp = (float*)(ws + 40960 + 2 * 2101248);
  float* Xp = (float*)(ws + 40960 + 3 * 2101248);

  detect_kernel<<<1, 256, 0, stream>>>((const uint4*)graph, flag);
  prep_kernel<<<204, 256, 0, stream>>>(query, key, value, Wq, Wk, Wv, bq, bk, bv,
                                       Qp, Kp, Vp);
  vsum_part_kernel<<<32, 256, 0, stream>>>(Vp, part);
  attn_sparse_kernel<<<BB * (SS - 3), 256, 0, stream>>>(Qp, Kp, Vp, part, graph, flag,
                                                        EK, EV, EQ, Xp);
  attn_dense_kernel<<<48, 256, 0, stream>>>(Qp, Kp, Vp, part, graph, flag,
                                            EK, EV, EQ, Xp);
  proj_kernel<<<dim3(65, 2), 256, 0, stream>>>(Xp, Wo, bo, out);
}

// Round 3
// 199.904 us; speedup vs baseline: 3.3881x; 1.6654x over previous
//
#include <hip/hip_runtime.h>
#include <hip/hip_bf16.h>

#define BB 2
#define SS 513
#define HH 512
#define NHH 8
#define DDIM 64

__device__ __forceinline__ float dot4(float4 a, float4 b) {
  return a.x * b.x + a.y * b.y + a.z * b.z + a.w * b.w;
}
__device__ __forceinline__ float4 add4(float4 a, float4 b) {
  return make_float4(a.x + b.x, a.y + b.y, a.z + b.z, a.w + b.w);
}

// ---------------------------------------------------------------------------
// Detect graph buffer layout: bool (1B/elem) vs int32/float32 (4B/elem).
__global__ __launch_bounds__(256) void detect_kernel(const uint4* __restrict__ gv,
                                                     int* __restrict__ flag) {
  __shared__ int s;
  if (threadIdx.x == 0) s = 0;
  __syncthreads();
  unsigned int local = 0;
  for (int i = threadIdx.x; i < 8192; i += 256) {  // 128 KB scan
    uint4 v = gv[i];
    local |= (v.x | v.y | v.z | v.w) & 0x0000ff00u;
  }
  if (local) atomicOr(&s, 1);
  __syncthreads();
  if (threadIdx.x == 0) *flag = s;
}

__device__ __forceinline__ bool graph_at(const void* g, int isBool, size_t idx) {
  if (isBool) return ((const unsigned char*)g)[idx] != 0;
  return ((const int*)g)[idx] != 0;
}

// ---------------------------------------------------------------------------
// Prep GEMV batch (grouped by position class). grid = 204.
__global__ __launch_bounds__(256) void prep_kernel(
    const float* __restrict__ Xq, const float* __restrict__ Xk, const float* __restrict__ Xv,
    const float* __restrict__ Wq, const float* __restrict__ Wk, const float* __restrict__ Wv,
    const float* __restrict__ Bq, const float* __restrict__ Bk, const float* __restrict__ Bv,
    float* __restrict__ Yq, float* __restrict__ Yk, float* __restrict__ Yv) {
  __shared__ float xs[16][HH];
  int idx = blockIdx.x;
  int tb = idx / 34, rem = idx % 34;
  int tensor = tb >> 1, b = tb & 1;
  int f, chunk;
  if (rem < 4)       { f = 0; chunk = rem; }
  else if (rem < 8)  { f = 1; chunk = rem - 4; }
  else if (rem < 12) { f = 2; chunk = rem - 8; }
  else if (rem < 23) { f = 3; chunk = rem - 12; }
  else               { f = 4; chunk = rem - 23; }
  const int count = (f < 3) ? 57 : 171;
  const float* X  = (tensor == 0) ? Xq : (tensor == 1) ? Xk : Xv;
  const float* W  = (tensor == 0) ? Wq : (tensor == 1) ? Wk : Wv;
  const float* Bi = (tensor == 0) ? Bq : (tensor == 1) ? Bk : Bv;
  float* Y        = (tensor == 0) ? Yq : (tensor == 1) ? Yk : Yv;
  const int tid = threadIdx.x;

  for (int r = 0; r < 16; ++r) {
    int i = chunk * 16 + r;
    if (i < count) {
      int t = (f < 3) ? (f + 9 * i) : (f + 2 * (i % 3) + 9 * (i / 3));
      const float* src = X + (size_t)(b * SS + t) * HH;
      xs[r][tid] = src[tid];
      xs[r][tid + 256] = src[tid + 256];
    }
  }
  __syncthreads();

  const int o0 = tid, o1 = tid + 256;
  const float* w0 = W + (size_t)f * HH * HH + (size_t)o0 * HH;
  const float* w1 = w0 + 256 * HH;
  float acc0[16], acc1[16];
#pragma unroll
  for (int r = 0; r < 16; ++r) { acc0[r] = 0.f; acc1[r] = 0.f; }
  for (int hc = 0; hc < HH / 4; ++hc) {
    float4 a = *(const float4*)(w0 + hc * 4);
    float4 c = *(const float4*)(w1 + hc * 4);
#pragma unroll
    for (int r = 0; r < 16; ++r) {
      float4 x4 = *(const float4*)&xs[r][hc * 4];
      acc0[r] += a.x * x4.x + a.y * x4.y + a.z * x4.z + a.w * x4.w;
      acc1[r] += c.x * x4.x + c.y * x4.y + c.z * x4.z + c.w * x4.w;
    }
  }
  float bs0 = 0.f, bs1 = 0.f;
#pragma unroll
  for (int ff = 0; ff < 5; ++ff) { bs0 += Bi[ff * HH + o0]; bs1 += Bi[ff * HH + o1]; }

  for (int r = 0; r < 16; ++r) {
    int i = chunk * 16 + r;
    if (i < count) {
      int t = (f < 3) ? (f + 9 * i) : (f + 2 * (i % 3) + 9 * (i / 3));
      float* dst = Y + (size_t)(b * SS + t) * HH;
      dst[o0] = acc0[r] + bs0;
      dst[o1] = acc1[r] + bs1;
    }
  }
}

// ---------------------------------------------------------------------------
// Partial V-sum over keys (for sparse all-masked rows).
__global__ __launch_bounds__(256) void vsum_part_kernel(const float* __restrict__ V,
                                                        float* __restrict__ part) {
  int idx = (blockIdx.x & 3) * 256 + threadIdx.x;
  int p = blockIdx.x >> 2;
  int b = idx >> 9, o = idx & 511;
  float acc = 0.f;
  for (int t = p; t < SS; t += 8)
    acc += V[(size_t)(b * SS + t) * HH + o];
  part[p * 1024 + idx] = acc;
}

// ---------------------------------------------------------------------------
// Sparse attention, q >= 3. One block per (b,q). Candidates {0,1,2,g,g+1}.
// Score phase: lane = (h, dg); all 8 heads in parallel, 3-shfl reduce.
__global__ __launch_bounds__(256) void attn_sparse_kernel(
    const float* __restrict__ Q, const float* __restrict__ K, const float* __restrict__ V,
    const float* __restrict__ vsumPart, const void* __restrict__ graph,
    const int* __restrict__ flag,
    const float* __restrict__ EK, const float* __restrict__ EV, const float* __restrict__ EQ,
    float* __restrict__ X) {
  __shared__ float sQ[HH];
  __shared__ float sW[5 * NHH];
  __shared__ float sRed[4 * 64];
  __shared__ int sUni;

  const int tid = threadIdx.x, lane = tid & 63, wv = tid >> 6;
  const int bid = blockIdx.x;
  const int b = bid / 510, q = 3 + bid % 510;
  const int row = b * SS + q;
  const int isBool = *flag;

  sQ[tid] = Q[(size_t)row * HH + tid];
  sQ[tid + 256] = Q[(size_t)row * HH + tid + 256];
  if (tid == 0) sUni = 0;
  __syncthreads();

  const int g = 3 + ((q - 3) >> 1) * 2;
  const size_t gbase = (size_t)b * SS * SS + (size_t)q * SS;
  const int h = lane >> 3, dg = lane & 7, d0 = dg * 8;

  // ---- scores: candidate c per wave; 8 heads x 8 d-groups per wave ----
  for (int c = wv; c < 5; c += 4) {
    int k = (c < 3) ? c : g + (c - 3);
    bool m = graph_at(graph, isBool, gbase + k);
    const float* ekp = EK + (gbase + k) * DDIM + d0;
    const float* eqp = EQ + ((size_t)(b * SS + k) * SS + q) * DDIM + d0;
    const float* kp  = K + (size_t)(b * SS + k) * HH + h * 64 + d0;
    const float* qp  = &sQ[h * 64 + d0];
    float4 ek0 = *(const float4*)ekp,      ek1 = *(const float4*)(ekp + 4);
    float4 eq0 = *(const float4*)eqp,      eq1 = *(const float4*)(eqp + 4);
    float4 kk0 = *(const float4*)kp,       kk1 = *(const float4*)(kp + 4);
    float4 qq0 = *(const float4*)qp,       qq1 = *(const float4*)(qp + 4);
    float p = dot4(add4(qq0, eq0), add4(kk0, ek0)) + dot4(add4(qq1, eq1), add4(kk1, ek1));
    p += __shfl_xor(p, 1);
    p += __shfl_xor(p, 2);
    p += __shfl_xor(p, 4);
    if (dg == 0) sW[c * NHH + h] = m ? p * 0.125f : -1e30f;
  }
  __syncthreads();

  // ---- softmax: wave 0, lane -> (h = lane>>3, c = lane&7) ----
  if (wv == 0) {
    int hh = lane >> 3, c = lane & 7;
    float s = (c < 5) ? sW[c * NHH + hh] : -1e30f;
    float mx = s;
#pragma unroll
    for (int off = 4; off; off >>= 1) mx = fmaxf(mx, __shfl_xor(mx, off));
    float e = (mx < -1e29f) ? 0.f : __expf(s - mx);
    float sum = e;
#pragma unroll
    for (int off = 4; off; off >>= 1) sum += __shfl_xor(sum, off);
    if (c < 5) sW[c * NHH + hh] = (mx < -1e29f) ? 0.f : e / sum;
    if (lane == 0 && mx < -1e29f) sUni = 1;  // mask is head-independent
  }
  __syncthreads();

  // ---- output ----
  if (sUni) {
    float acc = 0.f;
    for (int k = wv; k < SS; k += 4)
      acc += EV[(gbase + k) * DDIM + lane];
    sRed[wv * 64 + lane] = acc;
    __syncthreads();
    if (tid < 64) sRed[tid] = sRed[tid] + sRed[64 + tid] + sRed[128 + tid] + sRed[192 + tid];
    __syncthreads();
    const float c0 = 1.0f / 513.0f;
    for (int o = tid; o < HH; o += 256) {
      float vs = 0.f;
#pragma unroll
      for (int p = 0; p < 8; ++p) vs += vsumPart[p * 1024 + b * HH + o];
      X[(size_t)row * HH + o] = (vs + sRed[o & 63]) * c0;
    }
  } else {
#pragma unroll
    for (int rep = 0; rep < 2; ++rep) {
      int o = tid + rep * 256;
      int hh = o >> 6, d = o & 63;
      float acc = 0.f;
#pragma unroll
      for (int c = 0; c < 5; ++c) {
        int k = (c < 3) ? c : g + (c - 3);
        acc += sW[c * NHH + hh] *
               (V[(size_t)(b * SS + k) * HH + o] + EV[(gbase + k) * DDIM + d]);
      }
      X[(size_t)row * HH + o] = acc;
    }
  }
}

// ---------------------------------------------------------------------------
// Dense D1: scores for q<3. grid = 48*17. Wave: 8 keys x 1 head, lane=(kk,dg).
__global__ __launch_bounds__(256) void dense_score_kernel(
    const float* __restrict__ Q, const float* __restrict__ K,
    const void* __restrict__ graph, const int* __restrict__ flag,
    const float* __restrict__ EK, const float* __restrict__ EQ,
    float* __restrict__ sWS) {
  const int bid = blockIdx.x;
  const int bqh = bid / 17, ks = bid % 17;
  const int b = bqh / 24, r = bqh % 24, q = r >> 3, hd = r & 7;
  const int tid = threadIdx.x, lane = tid & 63, wv = tid >> 6;
  const int kk = lane >> 3, dg = lane & 7, d0 = dg * 8;
  const int isBool = *flag;
  const int k = ks * 32 + wv * 8 + kk;
  const int kc = (k < SS) ? k : (SS - 1);
  const size_t gbase = (size_t)b * SS * SS + (size_t)q * SS;
  const bool m = (k < SS) && graph_at(graph, isBool, gbase + kc);

  const float* qp  = Q + (size_t)(b * SS + q) * HH + hd * 64 + d0;
  const float* ekp = EK + (gbase + kc) * DDIM + d0;
  const float* eqp = EQ + ((size_t)(b * SS + kc) * SS + q) * DDIM + d0;
  const float* kp  = K + (size_t)(b * SS + kc) * HH + hd * 64 + d0;
  float4 qq0 = *(const float4*)qp,  qq1 = *(const float4*)(qp + 4);
  float4 ek0 = *(const float4*)ekp, ek1 = *(const float4*)(ekp + 4);
  float4 eq0 = *(const float4*)eqp, eq1 = *(const float4*)(eqp + 4);
  float4 kk0 = *(const float4*)kp,  kk1 = *(const float4*)(kp + 4);
  float p = dot4(add4(qq0, eq0), add4(kk0, ek0)) + dot4(add4(qq1, eq1), add4(kk1, ek1));
  p += __shfl_xor(p, 1);
  p += __shfl_xor(p, 2);
  p += __shfl_xor(p, 4);
  if (dg == 0 && k < SS)
    sWS[(size_t)bqh * SS + k] = m ? p * 0.125f : -1e30f;
}

// ---------------------------------------------------------------------------
// Dense D2: softmax over 513 per (b,q,h), in place. All-masked -> w=1/513 for
// every k (exactly the reference's uniform softmax of an all -1e5 row).
__global__ __launch_bounds__(256) void dense_softmax_kernel(float* __restrict__ sWS) {
  __shared__ float red[8];
  const int bqh = blockIdx.x;
  const int tid = threadIdx.x, lane = tid & 63, wv = tid >> 6;
  float* s = sWS + (size_t)bqh * SS;

  float mx = -3e38f;
  for (int k = tid; k < SS; k += 256) mx = fmaxf(mx, s[k]);
#pragma unroll
  for (int off = 32; off; off >>= 1) mx = fmaxf(mx, __shfl_xor(mx, off));
  if (lane == 0) red[wv] = mx;
  __syncthreads();
  mx = fmaxf(fmaxf(red[0], red[1]), fmaxf(red[2], red[3]));

  if (mx < -1e29f) {
    const float u = 1.0f / 513.0f;
    for (int k = tid; k < SS; k += 256) s[k] = u;
    return;
  }
  float sum = 0.f;
  for (int k = tid; k < SS; k += 256) sum += __expf(s[k] - mx);
#pragma unroll
  for (int off = 32; off; off >>= 1) sum += __shfl_xor(sum, off);
  if (lane == 0) red[4 + wv] = sum;
  __syncthreads();
  const float inv = 1.0f / (red[4] + red[5] + red[6] + red[7]);
  for (int k = tid; k < SS; k += 256) s[k] = __expf(s[k] - mx) * inv;
}

// ---------------------------------------------------------------------------
// Dense D3: partial weighted sums. grid = 48*8; block covers 65 keys.
__global__ __launch_bounds__(256) void dense_out_kernel(
    const float* __restrict__ V, const float* __restrict__ EV,
    const float* __restrict__ sWS, float* __restrict__ pOut) {
  __shared__ float sRed[4][DDIM];
  const int bqh = blockIdx.x >> 3, sl = blockIdx.x & 7;
  const int b = bqh / 24, r = bqh % 24, q = r >> 3, hd = r & 7;
  const int tid = threadIdx.x, lane = tid & 63, wv = tid >> 6;
  const size_t evbase = ((size_t)(b * SS + q) * SS) * DDIM;

  float acc = 0.f;
  for (int i = wv; i < 65; i += 4) {
    int k = sl * 65 + i;
    if (k < SS) {
      float w = sWS[(size_t)bqh * SS + k];
      acc += w * (V[(size_t)(b * SS + k) * HH + hd * 64 + lane] +
                  EV[evbase + (size_t)k * DDIM + lane]);
    }
  }
  sRed[wv][lane] = acc;
  __syncthreads();
  if (tid < 64)
    pOut[((size_t)bqh * 8 + sl) * DDIM + tid] =
        sRed[0][tid] + sRed[1][tid] + sRed[2][tid] + sRed[3][tid];
}

// ---------------------------------------------------------------------------
// Dense D4: combine 8 partials. grid = 48, block = 64.
__global__ __launch_bounds__(64) void dense_combine_kernel(
    const float* __restrict__ pOut, float* __restrict__ X) {
  const int bqh = blockIdx.x;
  const int b = bqh / 24, r = bqh % 24, q = r >> 3, hd = r & 7;
  const int d = threadIdx.x;
  float s = 0.f;
#pragma unroll
  for (int sl = 0; sl < 8; ++sl) s += pOut[((size_t)bqh * 8 + sl) * DDIM + d];
  X[(size_t)(b * SS + q) * HH + hd * 64 + d] = s;
}

// ---------------------------------------------------------------------------
// Output projection. grid = (65, 2).
__global__ __launch_bounds__(256) void proj_kernel(const float* __restrict__ Xin,
                                                   const float* __restrict__ Wo,
                                                   const float* __restrict__ bo,
                                                   float* __restrict__ out) {
  __shared__ float xs[16][HH];
  const int chunk = blockIdx.x;
  const int tid = threadIdx.x;
  const int NROW = BB * SS;
  for (int r = 0; r < 16; ++r) {
    int row = chunk * 16 + r;
    if (row < NROW) {
      const float* src = Xin + (size_t)row * HH;
      xs[r][tid] = src[tid];
      xs[r][tid + 256] = src[tid + 256];
    }
  }
  __syncthreads();
  const int o = blockIdx.y * 256 + tid;
  const float* w = Wo + (size_t)o * HH;
  float acc[16];
#pragma unroll
  for (int r = 0; r < 16; ++r) acc[r] = 0.f;
  for (int hc = 0; hc < HH / 4; ++hc) {
    float4 wv4 = *(const float4*)(w + hc * 4);
#pragma unroll
    for (int r = 0; r < 16; ++r) {
      float4 x4 = *(const float4*)&xs[r][hc * 4];
      acc[r] += wv4.x * x4.x + wv4.y * x4.y + wv4.z * x4.z + wv4.w * x4.w;
    }
  }
  const float bias = bo[o];
  for (int r = 0; r < 16; ++r) {
    int row = chunk * 16 + r;
    if (row < NROW) out[(size_t)row * HH + o] = acc[r] + bias;
  }
}

// ---------------------------------------------------------------------------
extern "C" void kernel_launch(void* const* d_in, const int* in_sizes, int n_in,
                              void* d_out, int out_size, void* d_ws, size_t ws_size,
                              hipStream_t stream) {
  (void)in_sizes; (void)n_in; (void)out_size; (void)ws_size;
  const float* query = (const float*)d_in[0];
  const float* key   = (const float*)d_in[1];
  const float* value = (const float*)d_in[2];
  const void*  graph = d_in[3];
  const float* EK = (const float*)d_in[4];
  const float* EV = (const float*)d_in[5];
  const float* EQ = (const float*)d_in[6];
  const float* Wq = (const float*)d_in[7];
  const float* bq = (const float*)d_in[8];
  const float* Wk = (const float*)d_in[9];
  const float* bk = (const float*)d_in[10];
  const float* Wv = (const float*)d_in[11];
  const float* bv = (const float*)d_in[12];
  const float* Wo = (const float*)d_in[13];
  const float* bo = (const float*)d_in[14];
  float* out = (float*)d_out;

  char* ws = (char*)d_ws;
  int*   flag = (int*)ws;                        // 4 B
  float* part = (float*)(ws + 256);              // 32 KB
  float* Qp = (float*)(ws + 40960);              // 2101248 B each
  float* Kp = (float*)(ws + 40960 + 2101248);
  float* Vp = (float*)(ws + 40960 + 2 * 2101248);
  float* Xp = (float*)(ws + 40960 + 3 * 2101248);
  float* sWS  = (float*)(ws + 40960 + 4 * 2101248);            // 48*513*4 = 98496 B
  float* pOut = (float*)(ws + 40960 + 4 * 2101248 + 98560);    // 48*8*64*4 = 98304 B

  detect_kernel<<<1, 256, 0, stream>>>((const uint4*)graph, flag);
  prep_kernel<<<204, 256, 0, stream>>>(query, key, value, Wq, Wk, Wv, bq, bk, bv,
                                       Qp, Kp, Vp);
  vsum_part_kernel<<<32, 256, 0, stream>>>(Vp, part);
  attn_sparse_kernel<<<BB * (SS - 3), 256, 0, stream>>>(Qp, Kp, Vp, part, graph, flag,
                                                        EK, EV, EQ, Xp);
  dense_score_kernel<<<48 * 17, 256, 0, stream>>>(Qp, Kp, graph, flag, EK, EQ, sWS);
  dense_softmax_kernel<<<48, 256, 0, stream>>>(sWS);
  dense_out_kernel<<<48 * 8, 256, 0, stream>>>(Vp, EV, sWS, pOut);
  dense_combine_kernel<<<48, 64, 0, stream>>>(pOut, Xp);
  proj_kernel<<<dim3(65, 2), 256, 0, stream>>>(Xp, Wo, bo, out);
}